// Round 2
// 1250.009 us; speedup vs baseline: 1.2130x; 1.2130x over previous
//
#include <hip/hip_runtime.h>

typedef unsigned short u16;
typedef unsigned int u32;
typedef float f32x4 __attribute__((ext_vector_type(4)));
typedef float f32x16 __attribute__((ext_vector_type(16)));
typedef short short8 __attribute__((ext_vector_type(8)));

#define DIM 128
#define NUM_NODE 43097
#define NV (NUM_NODE - 1)      // 43096 score columns
#define BB 4096
#define LL 50
#define NN (BB * LL)           // 204800 item nodes
#define EE (NN * 4)            // 819200 interact edges

__device__ __forceinline__ float b2f(u16 u) {
    union { u32 u; float f; } x; x.u = ((u32)u) << 16; return x.f;
}
__device__ __forceinline__ u16 f2b(float f) {
    union { float f; u32 u; } x; x.f = f;
    u32 r = x.u + 0x7FFFu + ((x.u >> 16) & 1u);
    return (u16)(r >> 16);
}

// ---------------- K0: fp32 -> bf16 conversion (pairs) ----------------------
__global__ __launch_bounds__(256) void k_cvt(
    const float* __restrict__ s, u16* __restrict__ d, int n2)
{
    int i = blockIdx.x * 256 + threadIdx.x;
    if (i < n2) {
        float2 v = ((const float2*)s)[i];
        ((u32*)d)[i] = (u32)f2b(v.x) | ((u32)f2b(v.y) << 16);
    }
}

// ---------------- K1: edge logits + deg count (16 lanes per edge) ----------
__global__ __launch_bounds__(256) void k_edge_logits(
    const u16* __restrict__ emb_bf, const float* __restrict__ pi_w,
    const int* __restrict__ iid, const int* __restrict__ int_src,
    const int* __restrict__ int_dst, float* __restrict__ logits,
    int* __restrict__ deg)
{
    int t = threadIdx.x;
    int e = blockIdx.x * 16 + (t >> 4);
    int i = t & 15;
    int s = int_src[e], d = int_dst[e];
    int sr = iid[s], dr = iid[d];
    uint4 ua = ((const uint4*)(emb_bf + (size_t)sr * DIM))[i];
    uint4 ub = ((const uint4*)(emb_bf + (size_t)dr * DIM))[i];
    const float4* p4 = (const float4*)pi_w;
    float4 w0 = p4[i * 2], w1 = p4[i * 2 + 1];
    float part =
        b2f((u16)ua.x) * w0.x * b2f((u16)ub.x) + b2f((u16)(ua.x >> 16)) * w0.y * b2f((u16)(ub.x >> 16)) +
        b2f((u16)ua.y) * w0.z * b2f((u16)ub.y) + b2f((u16)(ua.y >> 16)) * w0.w * b2f((u16)(ub.y >> 16)) +
        b2f((u16)ua.z) * w1.x * b2f((u16)ub.z) + b2f((u16)(ua.z >> 16)) * w1.y * b2f((u16)(ub.z >> 16)) +
        b2f((u16)ua.w) * w1.z * b2f((u16)ub.w) + b2f((u16)(ua.w >> 16)) * w1.w * b2f((u16)(ub.w >> 16));
    #pragma unroll
    for (int o = 1; o < 16; o <<= 1) part += __shfl_xor(part, o, 64);
    if (i == 0) {
        float lr = part >= 0.f ? part : 0.2f * part;   // leaky_relu 0.2
        logits[e] = lr;
        atomicAdd(&deg[d], 1);
    }
}

// ---------------- K2: exclusive scan of deg (3 kernels) --------------------
__global__ void k_block_sum(const int* __restrict__ deg, int* __restrict__ bsum)
{
    __shared__ int sm[256];
    int i = blockIdx.x * 256 + threadIdx.x;
    sm[threadIdx.x] = deg[i];
    __syncthreads();
    for (int s = 128; s > 0; s >>= 1) {
        if (threadIdx.x < s) sm[threadIdx.x] += sm[threadIdx.x + s];
        __syncthreads();
    }
    if (threadIdx.x == 0) bsum[blockIdx.x] = sm[0];
}

__global__ void k_scan_bsum(const int* __restrict__ bsum, int* __restrict__ boff)
{
    __shared__ int sm[1024];
    int t = threadIdx.x;
    int v = (t < 800) ? bsum[t] : 0;
    sm[t] = v;
    __syncthreads();
    for (int o = 1; o < 1024; o <<= 1) {
        int add = (t >= o) ? sm[t - o] : 0;
        __syncthreads();
        sm[t] += add;
        __syncthreads();
    }
    if (t < 800) boff[t] = sm[t] - v;   // exclusive
}

__global__ void k_scan_deg(const int* __restrict__ deg, const int* __restrict__ boff,
                           int* __restrict__ off)
{
    __shared__ int sm[256];
    int t = threadIdx.x;
    int i = blockIdx.x * 256 + t;
    int v = deg[i];
    sm[t] = v;
    __syncthreads();
    for (int o = 1; o < 256; o <<= 1) {
        int add = (t >= o) ? sm[t - o] : 0;
        __syncthreads();
        sm[t] += add;
        __syncthreads();
    }
    int incl = sm[t];
    int base = boff[blockIdx.x];
    off[i] = base + incl - v;
    if (i == NN - 1) off[NN] = base + incl;
}

// ---------------- K3: CSR fill ---------------------------------------------
__global__ void k_fill(const int* __restrict__ int_dst, const int* __restrict__ off,
                       int* __restrict__ cursor, int* __restrict__ e_sorted)
{
    int e = blockIdx.x * 256 + threadIdx.x;
    int d = int_dst[e];
    int slot = atomicAdd(&cursor[d], 1);
    e_sorted[off[d] + slot] = e;
}

// ---------------- K4: per-dst softmax + ft gather (16 lanes per dst) -------
__global__ __launch_bounds__(256) void k_softmax_ft(
    const u16* __restrict__ emb_bf, const int* __restrict__ iid,
    const int* __restrict__ int_src, const float* __restrict__ logits,
    const int* __restrict__ off, const int* __restrict__ e_sorted,
    u16* __restrict__ ft)
{
    int t = threadIdx.x;
    int dst = blockIdx.x * 16 + (t >> 4);
    int i = t & 15;
    int s0 = off[dst], s1 = off[dst + 1];
    uint4* outp = (uint4*)(ft + (size_t)dst * DIM);
    if (s0 == s1) { outp[i] = (uint4){0u, 0u, 0u, 0u}; return; }
    float m = -1e30f;
    for (int k = s0; k < s1; k++) m = fmaxf(m, logits[e_sorted[k]]);
    float a0 = 0.f, a1 = 0.f, a2 = 0.f, a3 = 0.f;
    float a4 = 0.f, a5 = 0.f, a6 = 0.f, a7 = 0.f, ssum = 0.f;
    for (int k = s0; k < s1; k++) {
        int e = e_sorted[k];
        float w = __expf(logits[e] - m);
        ssum += w;
        int row = iid[int_src[e]];
        uint4 u = ((const uint4*)(emb_bf + (size_t)row * DIM))[i];
        a0 += w * b2f((u16)u.x); a1 += w * b2f((u16)(u.x >> 16));
        a2 += w * b2f((u16)u.y); a3 += w * b2f((u16)(u.y >> 16));
        a4 += w * b2f((u16)u.z); a5 += w * b2f((u16)(u.z >> 16));
        a6 += w * b2f((u16)u.w); a7 += w * b2f((u16)(u.w >> 16));
    }
    float inv = 1.f / ssum;
    uint4 r;
    r.x = (u32)f2b(a0 * inv) | ((u32)f2b(a1 * inv) << 16);
    r.y = (u32)f2b(a2 * inv) | ((u32)f2b(a3 * inv) << 16);
    r.z = (u32)f2b(a4 * inv) | ((u32)f2b(a5 * inv) << 16);
    r.w = (u32)f2b(a6 * inv) | ((u32)f2b(a7 * inv) << 16);
    outp[i] = r;
}

// ---------------- K5: session mean + f = [h_t, mean] @ r_w^T ---------------
__global__ __launch_bounds__(128) void k_mean_f(
    const u16* __restrict__ ft, const float* __restrict__ target_emb,
    const float* __restrict__ r_w, const int* __restrict__ tid,
    float* __restrict__ fmat)
{
    __shared__ float sht[DIM], smean[DIM];
    __shared__ float part[2][DIM];
    int b = blockIdx.x, t = threadIdx.x;
    int w = t >> 6, c = t & 63;
    size_t j0 = (size_t)b * LL;
    float sx = 0.f, sy = 0.f;
    for (int i = w; i < LL; i += 2) {
        u32 v = ((const u32*)(ft + (j0 + i) * DIM))[c];
        sx += b2f((u16)v); sy += b2f((u16)(v >> 16));
    }
    part[w][2 * c] = sx; part[w][2 * c + 1] = sy;
    sht[t] = target_emb[(size_t)tid[b] * DIM + t];
    __syncthreads();
    smean[t] = (part[0][t] + part[1][t]) * (1.f / (float)LL);
    __syncthreads();
    const float2* rw = (const float2*)(r_w + (size_t)t * 2 * DIM);
    float acc = 0.f;
    #pragma unroll 8
    for (int k = 0; k < 64; k++) {
        float2 u = rw[k];
        acc += sht[2 * k] * u.x + sht[2 * k + 1] * u.y;
    }
    #pragma unroll 8
    for (int k = 0; k < 64; k++) {
        float2 u = rw[64 + k];
        acc += smean[2 * k] * u.x + smean[2 * k + 1] * u.y;
    }
    fmat[(size_t)b * DIM + t] = acc;
}

// ---------------- K6: fused e2-GEMM + tanh + coef (32x32 MFMA, no LDS) -----
// A[j, 0:256] = [ft[j] | pos_emb[pid[j]]], W = q_w[128,256]; coef[j]=tanh(AW^T)·f[sess]
__global__ __launch_bounds__(256) void k_coef(
    const u16* __restrict__ ft, const u16* __restrict__ pos_bf,
    const u16* __restrict__ qw_bf, const int* __restrict__ pid,
    const int* __restrict__ agg_dst, const float* __restrict__ fmat,
    float* __restrict__ coef)
{
    int j0 = blockIdx.x * 128;
    int t = threadIdx.x;
    int wave = t >> 6, lane = t & 63;
    int l31 = lane & 31, half = lane >> 5;
    int m0 = wave * 32;
    int myrow = j0 + m0 + l31;
    const u16* aft  = ft + (size_t)myrow * DIM;
    const u16* apos = pos_bf + (size_t)pid[myrow] * DIM;

    f32x16 acc[4];
    #pragma unroll
    for (int nt = 0; nt < 4; nt++)
        #pragma unroll
        for (int q = 0; q < 16; q++) acc[nt][q] = 0.f;

    #pragma unroll
    for (int h = 0; h < 2; h++) {
        const u16* arow = h ? apos : aft;
        #pragma unroll
        for (int ks = 0; ks < 8; ks++) {
            short8 a = *(const short8*)(arow + ks * 16 + half * 8);
            #pragma unroll
            for (int nt = 0; nt < 4; nt++) {
                short8 b = *(const short8*)(qw_bf + (size_t)(nt * 32 + l31) * (2 * DIM)
                                            + h * DIM + ks * 16 + half * 8);
                acc[nt] = __builtin_amdgcn_mfma_f32_32x32x16_bf16(a, b, acc[nt], 0, 0, 0);
            }
        }
    }

    // epilogue: coef[j] = sum_n tanh(e2[j,n]) * f[sess][n]
    float p[16];
    #pragma unroll
    for (int reg = 0; reg < 16; reg++) {
        int j = j0 + m0 + (reg & 3) + 8 * (reg >> 2) + 4 * half;
        int sess = agg_dst[j];
        const float* fr = fmat + (size_t)sess * DIM;
        float s = 0.f;
        #pragma unroll
        for (int nt = 0; nt < 4; nt++) {
            float x = acc[nt][reg];
            x = fminf(fmaxf(x, -15.f), 15.f);
            float e2x = __expf(2.f * x);
            float th = (e2x - 1.f) / (e2x + 1.f);
            s += th * fr[nt * 32 + l31];
        }
        p[reg] = s;
    }
    #pragma unroll
    for (int o = 1; o < 32; o <<= 1)
        #pragma unroll
        for (int reg = 0; reg < 16; reg++)
            p[reg] += __shfl_xor(p[reg], o, 64);
    if (l31 == 0) {
        #pragma unroll
        for (int reg = 0; reg < 16; reg++)
            coef[j0 + m0 + (reg & 3) + 8 * (reg >> 2) + 4 * half] = p[reg];
    }
}

// ---------------- K7: select[b] = sum_j ft[j]*coef[j] ----------------------
__global__ __launch_bounds__(128) void k_select(
    const u16* __restrict__ ft, const float* __restrict__ coef,
    u16* __restrict__ selectb)
{
    __shared__ float part[2][DIM];
    int b = blockIdx.x, t = threadIdx.x;
    int w = t >> 6, c = t & 63;
    size_t j0 = (size_t)b * LL;
    float sx = 0.f, sy = 0.f;
    for (int i = w; i < LL; i += 2) {
        size_t j = j0 + i;
        float cf = coef[j];
        u32 v = ((const u32*)(ft + j * DIM))[c];
        sx += cf * b2f((u16)v); sy += cf * b2f((u16)(v >> 16));
    }
    part[w][2 * c] = sx; part[w][2 * c + 1] = sy;
    __syncthreads();
    if (t < 64) {
        float x0 = part[0][2 * t] + part[1][2 * t];
        float x1 = part[0][2 * t + 1] + part[1][2 * t + 1];
        ((u32*)(selectb + (size_t)b * DIM))[t] = (u32)f2b(x0) | ((u32)f2b(x1) << 16);
    }
}

// ---------------- K8: scores = select @ emb[1:]^T (32x32 MFMA, NT stores) --
// grid: (m-tiles, n-tiles) — m varies fastest so consecutive blocks share B-tile
__global__ __launch_bounds__(256) void k_scores(
    const u16* __restrict__ selectb, const u16* __restrict__ emb_bf,
    float* __restrict__ out)
{
    int m0v = blockIdx.x * 128;
    int n0  = blockIdx.y * 128;
    int t = threadIdx.x;
    int wave = t >> 6, lane = t & 63;
    int l31 = lane & 31, half = lane >> 5;
    const u16* A = selectb + (size_t)(m0v + wave * 32 + l31) * DIM;

    f32x16 acc[4];
    #pragma unroll
    for (int nt = 0; nt < 4; nt++)
        #pragma unroll
        for (int q = 0; q < 16; q++) acc[nt][q] = 0.f;

    #pragma unroll
    for (int ks = 0; ks < 8; ks++) {
        short8 a = *(const short8*)(A + ks * 16 + half * 8);
        #pragma unroll
        for (int nt = 0; nt < 4; nt++) {
            int v = n0 + nt * 32 + l31;
            int er = v + 1;
            if (er > NV) er = NV;           // clamp tail reads (emb row 43096 valid)
            short8 b = *(const short8*)(emb_bf + (size_t)er * DIM + ks * 16 + half * 8);
            acc[nt] = __builtin_amdgcn_mfma_f32_32x32x16_bf16(a, b, acc[nt], 0, 0, 0);
        }
    }
    // 32x32 C layout: col = lane&31 (32 consecutive cols = 128B line per half-wave)
    #pragma unroll
    for (int reg = 0; reg < 16; reg++) {
        int row = m0v + wave * 32 + (reg & 3) + 8 * (reg >> 2) + 4 * half;
        float* orow = out + (size_t)row * NV;
        #pragma unroll
        for (int nt = 0; nt < 4; nt++) {
            int v = n0 + nt * 32 + l31;
            if (v < NV) __builtin_nontemporal_store(acc[nt][reg], &orow[v]);
        }
    }
}

// ---------------- launch ---------------------------------------------------
extern "C" void kernel_launch(void* const* d_in, const int* in_sizes, int n_in,
                              void* d_out, int out_size, void* d_ws, size_t ws_size,
                              hipStream_t stream)
{
    const float* emb        = (const float*)d_in[0];
    const float* pos_emb    = (const float*)d_in[1];
    const float* target_emb = (const float*)d_in[2];
    const float* pi_w       = (const float*)d_in[3];
    const float* q_w        = (const float*)d_in[4];
    const float* r_w        = (const float*)d_in[5];
    const int* iid          = (const int*)d_in[6];
    const int* pid          = (const int*)d_in[7];
    const int* tid          = (const int*)d_in[8];
    const int* int_src      = (const int*)d_in[9];
    const int* int_dst      = (const int*)d_in[10];
    const int* agg_dst      = (const int*)d_in[12];
    float* out = (float*)d_out;

    char* ws = (char*)d_ws;
    u16*   emb_bf  = (u16*)  (ws + 0);                        // 43097*128*2 = 11,032,832
    u16*   pos_bf  = (u16*)  (ws + 11032832);                 // 200*128*2 = 51,200
    u16*   qw_bf   = (u16*)  (ws + 11084032);                 // 128*256*2 = 65,536
    float* logits  = (float*)(ws + 11149568);                 // E*4
    int*   deg     = (int*)  (ws + 14426368);                 // N*4
    int*   off     = (int*)  (ws + 15245568);                 // (N+1)*4
    int*   cursor  = (int*)  (ws + 16065024);                 // N*4
    int*   bsum    = (int*)  (ws + 16884224);                 // 800*4
    int*   boff    = (int*)  (ws + 16887424);                 // 800*4
    int*   e_sorted= (int*)  (ws + 16890880);                 // E*4
    u16*   ft      = (u16*)  (ws + 20167680);                 // N*128*2
    float* fmat    = (float*)(ws + 72596480);                 // B*128*4
    float* coef    = (float*)(ws + 74693632);                 // N*4
    u16*   selectb = (u16*)  (ws + 75512832);                 // B*128*2  (ends 76,561,408)

    hipMemsetAsync(deg, 0, NN * sizeof(int), stream);
    hipMemsetAsync(cursor, 0, NN * sizeof(int), stream);

    k_cvt<<<(NUM_NODE * DIM / 2 + 255) / 256, 256, 0, stream>>>(emb, emb_bf, NUM_NODE * DIM / 2);
    k_cvt<<<(200 * DIM / 2 + 255) / 256, 256, 0, stream>>>(pos_emb, pos_bf, 200 * DIM / 2);
    k_cvt<<<(DIM * 2 * DIM / 2 + 255) / 256, 256, 0, stream>>>(q_w, qw_bf, DIM * 2 * DIM / 2);

    k_edge_logits<<<EE / 16, 256, 0, stream>>>(emb_bf, pi_w, iid, int_src, int_dst, logits, deg);
    k_block_sum<<<NN / 256, 256, 0, stream>>>(deg, bsum);
    k_scan_bsum<<<1, 1024, 0, stream>>>(bsum, boff);
    k_scan_deg<<<NN / 256, 256, 0, stream>>>(deg, boff, off);
    k_fill<<<EE / 256, 256, 0, stream>>>(int_dst, off, cursor, e_sorted);
    k_softmax_ft<<<NN / 16, 256, 0, stream>>>(emb_bf, iid, int_src, logits, off, e_sorted, ft);
    k_mean_f<<<BB, 128, 0, stream>>>(ft, target_emb, r_w, tid, fmat);
    k_coef<<<NN / 128, 256, 0, stream>>>(ft, pos_bf, qw_bf, pid, agg_dst, fmat, coef);
    k_select<<<BB, 128, 0, stream>>>(ft, coef, selectb);
    dim3 g8(BB / 128, (NV + 127) / 128);
    k_scores<<<g8, 256, 0, stream>>>(selectb, emb_bf, out);
}